// Round 4
// baseline (13187.457 us; speedup 1.0000x reference)
//
#include <hip/hip_runtime.h>
#include <hip/hip_bf16.h>

#define NPX 6912   // 96*72
typedef unsigned long long u64;
typedef short bf16x8 __attribute__((ext_vector_type(8)));
typedef float f32x4 __attribute__((ext_vector_type(4)));

__device__ __forceinline__ int ea_from_bits(u64 bits){
    double m = __longlong_as_double((long long)bits);
    if (!(m > 0.0)) return 0;
    return ilogb(m) + 1;
}

// ---------------- diff = y - x (exact, f64) ----------------
__global__ __launch_bounds__(256) void diff_kd(const float* __restrict__ x,
                                               const float* __restrict__ y,
                                               double* __restrict__ d, int n){
    int i = blockIdx.x*256 + threadIdx.x;
    if (i < n) d[i] = (double)y[i] - (double)x[i];
}

// ---------------- 1x1 conv 17->128 + bn, fp64 ----------------
__global__ __launch_bounds__(256) void conv1x1_d(const double* __restrict__ in,
    const float* __restrict__ wgt, const float* __restrict__ scale,
    const float* __restrict__ shift, double* __restrict__ out){
    __shared__ float Ws[17*128];
    const int t = threadIdx.x;
    for (int e=t; e<17*128; e+=256){
        int ic = e >> 7, oc = e & 127;
        Ws[e] = wgt[oc*17 + ic];
    }
    __syncthreads();
    const int pxl = t & 31, ocg = t >> 5;
    const int p = blockIdx.x*32 + pxl;
    const int b = p / NPX, pi = p - b*NPX;
    double acc[16];
    #pragma unroll
    for (int j=0;j<16;j++) acc[j]=0.0;
    const double* inb = in + (size_t)b*17*NPX + pi;
    #pragma unroll
    for (int ic=0;ic<17;ic++){
        const double a = inb[(size_t)ic*NPX];
        #pragma unroll
        for (int j=0;j<16;j++) acc[j] = fma(a, (double)Ws[(ic<<7)+(ocg<<4)+j], acc[j]);
    }
    #pragma unroll
    for (int j=0;j<16;j++){
        const int oc = (ocg<<4)+j;
        out[((size_t)b*128+oc)*NPX + pi] = fma(acc[j], (double)scale[oc], (double)shift[oc]);
    }
}

// ---------------- generic 3x3 conv fp64 (blk0 only now) ----------------
template<typename OutT>
__global__ __launch_bounds__(256) void conv3x3d(
    const double* __restrict__ in, const float* __restrict__ wgt,
    const float* __restrict__ scale, const float* __restrict__ shift,
    const double* res, OutT* out,
    int IC, int OCt, int dil, int relu)
{
    __shared__ double As[36*64];
    __shared__ float  Bs[36*132];
    const int t = threadIdx.x;
    const int p0 = blockIdx.x << 6;
    const int b  = p0 / NPX;
    const int pi0 = p0 - b*NPX;
    const int oc0 = blockIdx.y << 7;
    const int pxg = t & 15, ocg = t >> 4;
    const int IC9 = IC*9;

    int offA[9]; unsigned maskA = 0;
    #pragma unroll
    for (int i=0;i<9;i++){
        const int e = t + (i<<8);
        const int k = e >> 6, px = e & 63;
        const int ic = k/9, tap = k - ic*9;
        const int dy = (tap/3 - 1)*dil, dx = (tap - (tap/3)*3 - 1)*dil;
        const int pi = pi0 + px;
        const int yq = pi/72;
        const int yy = yq + dy, xx = pi - yq*72 + dx;
        offA[i] = ic*NPX + yy*72 + xx;
        if ((unsigned)yy < 96u && (unsigned)xx < 72u) maskA |= (1u<<i);
    }
    int offB[18]; unsigned maskB = 0;
    #pragma unroll
    for (int i=0;i<18;i++){
        const int e = t + (i<<8);
        const int oc = e/36, ki = e - oc*36;
        offB[i] = (oc0+oc)*IC9 + ki;
        if (oc0+oc < OCt) maskB |= (1u<<i);
    }

    double ra[9]; float rb[18];
    double acc[4][8];
    #pragma unroll
    for (int i=0;i<4;i++)
      #pragma unroll
      for (int j=0;j<8;j++) acc[i][j]=0.0;

    const double* inb = in + (size_t)b*IC*NPX;

    auto loadRegs = [&](int ic0c, int icc9){
        const double* ia = inb + (size_t)ic0c*NPX;
        const float*  wb = wgt + ic0c*9;
        if (icc9 == 36){
            #pragma unroll
            for (int i=0;i<9;i++)
                ra[i] = (maskA>>i & 1u) ? ia[offA[i]] : 0.0;
            #pragma unroll
            for (int i=0;i<18;i++)
                rb[i] = (maskB>>i & 1u) ? wb[offB[i]] : 0.f;
        } else {
            #pragma unroll
            for (int i=0;i<9;i++){
                const int k = (t>>6) + (i<<2);
                ra[i] = ((maskA>>i & 1u) && k < icc9) ? ia[offA[i]] : 0.0;
            }
            #pragma unroll
            for (int i=0;i<18;i++){
                const int e = t + (i<<8);
                const int ki = e - (e/36)*36;
                rb[i] = ((maskB>>i & 1u) && ki < icc9) ? wb[offB[i]] : 0.f;
            }
        }
    };
    auto writeLDS = [&](){
        #pragma unroll
        for (int i=0;i<9;i++) As[t + (i<<8)] = ra[i];
        #pragma unroll
        for (int i=0;i<18;i++){
            const int e = t + (i<<8);
            const int oc = e/36, ki = e - oc*36;
            Bs[ki*132 + oc] = rb[i];
        }
    };
    auto compute = [&](){
        #pragma unroll 2
        for (int k=0;k<36;k++){
            const double* ar = As + (k<<6) + (pxg<<2);
            const float4 b0 = *(const float4*)(Bs + k*132 + (ocg<<3));
            const float4 b1 = *(const float4*)(Bs + k*132 + (ocg<<3) + 4);
            const double a0=ar[0], a1=ar[1], a2=ar[2], a3=ar[3];
            const double bb[8] = {(double)b0.x,(double)b0.y,(double)b0.z,(double)b0.w,
                                  (double)b1.x,(double)b1.y,(double)b1.z,(double)b1.w};
            #pragma unroll
            for (int j=0;j<8;j++){
                acc[0][j] = fma(a0, bb[j], acc[0][j]);
                acc[1][j] = fma(a1, bb[j], acc[1][j]);
                acc[2][j] = fma(a2, bb[j], acc[2][j]);
                acc[3][j] = fma(a3, bb[j], acc[3][j]);
            }
        }
    };

    const int nchunk = (IC+3)>>2;
    loadRegs(0, (IC < 4 ? IC : 4)*9);
    writeLDS();
    __syncthreads();
    for (int c=0;c<nchunk;c++){
        const int icn = (c+1)<<2;
        const bool more = icn < IC;
        if (more){
            int iccn = IC - icn; if (iccn > 4) iccn = 4;
            loadRegs(icn, iccn*9);
        }
        compute();
        __syncthreads();
        if (more){ writeLDS(); __syncthreads(); }
    }

    const int pxb = pi0 + (pxg<<2);
    #pragma unroll
    for (int j=0;j<8;j++){
        const int oc = oc0 + (ocg<<3) + j;
        if (oc < OCt){
            const double sc = scale ? (double)scale[oc] : 1.0;
            const double sh = shift ? (double)shift[oc] : 0.0;
            const size_t ob = ((size_t)b*OCt+oc)*NPX + pxb;
            #pragma unroll
            for (int i=0;i<4;i++){
                double v = fma(acc[i][j], sc, sh);
                if (res)  v += res[ob+i];
                if (relu) v = v > 0.0 ? v : 0.0;
                out[ob+i] = (OutT)v;
            }
        }
    }
}

// ---------------- tensor absmax -> maxbuf[slot] ----------------
__global__ __launch_bounds__(256) void maxk(const double* __restrict__ src, int n,
                                            u64* maxbuf, int slot){
    double m = 0.0;
    for (int i = blockIdx.x*256 + threadIdx.x; i < n; i += gridDim.x*256)
        m = fmax(m, fabs(src[i]));
    #pragma unroll
    for (int o = 32; o; o >>= 1) m = fmax(m, __shfl_down(m, o));
    __shared__ double W[4];
    if ((threadIdx.x & 63) == 0) W[threadIdx.x>>6] = m;
    __syncthreads();
    if (threadIdx.x == 0){
        m = fmax(fmax(W[0],W[1]), fmax(W[2],W[3]));
        atomicMax(maxbuf + slot, (u64)__double_as_longlong(m));
    }
}

// ---------------- activation limb decompose: f64 [2][128][NPX] -> bf16 [4][2][PS][128] ----
__global__ __launch_bounds__(256) void adecomp_k(const double* __restrict__ src,
    __hip_bfloat16* __restrict__ dst, const u64* __restrict__ maxbuf, int slot,
    int PS, int PW, int PB)
{
    __shared__ __hip_bfloat16 L[4][32][128];
    const int t = threadIdx.x;
    const int b = blockIdx.x / 108, pi0 = (blockIdx.x % 108)*64;
    const int sh = 30 - ea_from_bits(maxbuf[slot]);
    const int tc = t >> 5, tp = t & 31;   // 8 c-lanes x 32 px
    const int wic = t & 15, wpx = t >> 4; // 16 px x 16 ic-chunks
    for (int half = 0; half < 2; half++){
        const int p0 = pi0 + half*32;
        __syncthreads();
        for (int c = tc; c < 128; c += 8){
            double a = src[((size_t)b*128 + c)*NPX + p0 + tp];
            long long q = __double2ll_rn(ldexp(a, sh));
            int d3 = (int)(((q + 128) & 255) - 128); q = (q - d3) >> 8;
            int d2 = (int)(((q + 128) & 255) - 128); q = (q - d2) >> 8;
            int d1 = (int)(((q + 128) & 255) - 128);
            int d0 = (int)((q - d1) >> 8);
            L[0][tp][c] = __float2bfloat16((float)d0);
            L[1][tp][c] = __float2bfloat16((float)d1);
            L[2][tp][c] = __float2bfloat16((float)d2);
            L[3][tp][c] = __float2bfloat16((float)d3);
        }
        __syncthreads();
        #pragma unroll
        for (int l = 0; l < 4; l++){
            #pragma unroll
            for (int g = 0; g < 2; g++){
                int px = wpx + g*16;
                int pip = p0 + px;
                int yy = pip/72, xx = pip - yy*72;
                size_t po = ((size_t)(l*2 + b)*PS + (size_t)(yy+PB)*PW + (xx+PB))*(size_t)128 + wic*8;
                *(uint4*)(dst + po) = *(const uint4*)(&L[l][px][wic*8]);
            }
        }
    }
}

// ---------------- weight limb prepack: fp32 [ocw][128][9] -> bf16 [4][9][OCpad][128] + Eb ----
__global__ __launch_bounds__(64) void wprep_k(const float* __restrict__ wgt,
    __hip_bfloat16* __restrict__ Bpk, int* __restrict__ Eb, int ocw, int OCpad)
{
    const int oc = blockIdx.x;
    const int t = threadIdx.x;
    const int NW = 128*9;
    float m = 0.f;
    if (oc < ocw){
        for (int e = t; e < NW; e += 64) m = fmaxf(m, fabsf(wgt[(size_t)oc*NW + e]));
    }
    #pragma unroll
    for (int o = 32; o; o >>= 1) m = fmaxf(m, __shfl_down(m, o));
    m = __shfl(m, 0);
    const int Ebv = (m > 0.f) ? (ilogbf(m) + 1) : 0;
    if (t == 0) Eb[oc] = Ebv;
    const int sh = 30 - Ebv;
    const size_t LS = (size_t)9*OCpad*128;
    for (int e = t; e < NW; e += 64){
        float w = (oc < ocw) ? wgt[(size_t)oc*NW + e] : 0.f;
        long long q = __double2ll_rn(ldexp((double)w, sh));
        int d3 = (int)(((q + 128) & 255) - 128); q = (q - d3) >> 8;
        int d2 = (int)(((q + 128) & 255) - 128); q = (q - d2) >> 8;
        int d1 = (int)(((q + 128) & 255) - 128);
        int d0 = (int)((q - d1) >> 8);
        const int ic = e / 9, tap = e - ic*9;
        const size_t base = ((size_t)tap*OCpad + oc)*(size_t)128 + ic;
        Bpk[0*LS + base] = __float2bfloat16((float)d0);
        Bpk[1*LS + base] = __float2bfloat16((float)d1);
        Bpk[2*LS + base] = __float2bfloat16((float)d2);
        Bpk[3*LS + base] = __float2bfloat16((float)d3);
    }
}

// ---------------- exact limb-MFMA 3x3 dilated conv ----------------
// grid (216, OCpad/64), 256 thr (4 waves, each 32px x 32oc of the 64x64 tile)
// MODE 0: trunk relu(bn(conv))->f64 + max ; 1: trunk relu(bn(conv)+res)->f64 + max
// MODE 2: offset conv -> f32 raw
#define MF(A,B,C) __builtin_amdgcn_mfma_f32_16x16x32_bf16(A,B,C,0,0,0)
#define DRAIN(CS, WT) do { \
  _Pragma("unroll") for (int mt_=0; mt_<2; mt_++){ \
  _Pragma("unroll") for (int nt_=0; nt_<2; nt_++){ \
  _Pragma("unroll") for (int v_=0; v_<4; v_++){ \
    cr[mt_][nt_][v_] += (double)CS[mt_][nt_][v_]*(WT); CS[mt_][nt_][v_] = 0.f; } } } } while(0)

template<int MODE>
__global__ __launch_bounds__(256) void convL(
    const __hip_bfloat16* __restrict__ inL, int PS, int PW, int PB, int dil,
    const __hip_bfloat16* __restrict__ Bpk, const int* __restrict__ Eb, int OCpad, int OCw,
    const u64* __restrict__ maxbuf, int easlot,
    const float* __restrict__ scale, const float* __restrict__ shift,
    const double* res, void* outp, u64* maxout, int moslot)
{
    __shared__ __align__(16) short LSD[16384];   // As[4][4][64][8] | Bs[4][4][64][8]
    short* As = LSD;
    short* Bs = LSD + 8192;
    const int t = threadIdx.x;
    const int b = blockIdx.x / 108, pi0 = (blockIdx.x % 108)*64;
    const int oc0 = blockIdx.y * 64;
    const int spx = t & 63, so = t >> 6;
    const int pi = pi0 + spx;
    const int sy = pi/72, sx = pi - sy*72;
    const long long apix = (long long)(sy+PB)*PW + (sx+PB);
    const long long planeStride = (long long)2*PS*128;
    const long long aTh = (long long)b*PS*128 + so*8;
    const long long bTh = (long long)(oc0 + spx)*128 + so*8;
    const size_t bLimb = (size_t)9*OCpad*128;

    const int lane = t & 63, w = t >> 6;
    const int wm = w & 1, wn = w >> 1;
    const int ocl = lane & 15, rq = lane >> 4;

    f32x4 c0[2][2], c1[2][2], c2[2][2], c3[2][2];
    double cr[2][2][4];
    #pragma unroll
    for (int i=0;i<2;i++)
      #pragma unroll
      for (int j=0;j<2;j++){
        c0[i][j]=(f32x4)(0.f); c1[i][j]=(f32x4)(0.f);
        c2[i][j]=(f32x4)(0.f); c3[i][j]=(f32x4)(0.f);
        #pragma unroll
        for (int v=0;v<4;v++) cr[i][j][v]=0.0;
      }

    const int Ea = ea_from_bits(maxbuf[easlot]);

    // LDS frag read offsets (shorts)
    const int aRd0 = rq*512 + (wm*32 + ocl)*8;       // + mt*16*8 + l*2048
    const int bRd0 = rq*512 + (wn*32 + ocl)*8;       // + nt*16*8 + l*2048

    for (int c = 0; c < 36; c++){
        const int tap = c >> 2, icc = c & 3;
        const int ty = tap/3, tx = tap - ty*3;
        const long long dofs = ((long long)(ty-1)*PW + (tx-1))*dil;
        const long long aoff = (apix + dofs)*128 + icc*32 + aTh;
        const long long boff = ((long long)tap*OCpad)*128 + icc*32 + bTh;
        uint4 ra[4], rb[4];
        #pragma unroll
        for (int l = 0; l < 4; l++){
            ra[l] = *(const uint4*)(inL + (aoff + (long long)l*planeStride));
            rb[l] = *(const uint4*)(Bpk + ((size_t)l*bLimb + boff));
        }
        __syncthreads();
        #pragma unroll
        for (int l = 0; l < 4; l++){
            *(uint4*)(As + l*2048 + t*8) = ra[l];
            *(uint4*)(Bs + l*2048 + t*8) = rb[l];
        }
        __syncthreads();

        bf16x8 af[2][4];
        #pragma unroll
        for (int mt = 0; mt < 2; mt++)
          #pragma unroll
          for (int l = 0; l < 4; l++)
            af[mt][l] = *(const bf16x8*)(As + l*2048 + aRd0 + mt*128);
        #pragma unroll
        for (int nt = 0; nt < 2; nt++){
            bf16x8 bfr[4];
            #pragma unroll
            for (int l = 0; l < 4; l++)
                bfr[l] = *(const bf16x8*)(Bs + l*2048 + bRd0 + nt*128);
            #pragma unroll
            for (int mt = 0; mt < 2; mt++){
                c0[mt][nt] = MF(af[mt][0], bfr[0], c0[mt][nt]);
                c1[mt][nt] = MF(af[mt][0], bfr[1], c1[mt][nt]);
                c1[mt][nt] = MF(af[mt][1], bfr[0], c1[mt][nt]);
                c2[mt][nt] = MF(af[mt][0], bfr[2], c2[mt][nt]);
                c2[mt][nt] = MF(af[mt][1], bfr[1], c2[mt][nt]);
                c2[mt][nt] = MF(af[mt][2], bfr[0], c2[mt][nt]);
                c3[mt][nt] = MF(af[mt][0], bfr[3], c3[mt][nt]);
                c3[mt][nt] = MF(af[mt][1], bfr[2], c3[mt][nt]);
                c3[mt][nt] = MF(af[mt][2], bfr[1], c3[mt][nt]);
                c3[mt][nt] = MF(af[mt][3], bfr[0], c3[mt][nt]);
            }
        }
        // exactness drains (int sums must stay < 2^24 in fp32)
        if (c == 17) DRAIN(c1, 0x1p-8);
        if ((c % 9) == 8){ DRAIN(c2, 0x1p-16); DRAIN(c3, 0x1p-24); }
    }
    DRAIN(c0, 1.0);
    DRAIN(c1, 0x1p-8);
    DRAIN(c2, 0x1p-16);
    DRAIN(c3, 0x1p-24);

    double mx = 0.0;
    #pragma unroll
    for (int nt = 0; nt < 2; nt++){
        const int oc = oc0 + wn*32 + nt*16 + ocl;
        const int ex = Ea + Eb[oc] - 12;
        double sc = 1.0, sf = 0.0;
        if (MODE != 2){ sc = (double)scale[oc]; sf = (double)shift[oc]; }
        #pragma unroll
        for (int mt = 0; mt < 2; mt++){
            #pragma unroll
            for (int v = 0; v < 4; v++){
                const int px = wm*32 + mt*16 + rq*4 + v;
                double dv = ldexp(cr[mt][nt][v], ex);
                if (MODE == 2){
                    if (oc < OCw)
                        ((float*)outp)[((size_t)b*OCw + oc)*NPX + pi0 + px] = (float)dv;
                } else {
                    dv = fma(dv, sc, sf);
                    if (MODE == 1) dv += res[((size_t)(b*128 + oc))*NPX + pi0 + px];
                    dv = dv > 0.0 ? dv : 0.0;
                    ((double*)outp)[((size_t)(b*128 + oc))*NPX + pi0 + px] = dv;
                    mx = fmax(mx, dv);
                }
            }
        }
    }
    if (MODE != 2){
        #pragma unroll
        for (int o = 32; o; o >>= 1) mx = fmax(mx, __shfl_down(mx, o));
        __shared__ double MW[4];
        if (lane == 0) MW[w] = mx;
        __syncthreads();
        if (t == 0)
            atomicMax(maxout + moslot,
                      (u64)__double_as_longlong(fmax(fmax(MW[0],MW[1]), fmax(MW[2],MW[3]))));
    }
}

// ---------------- deformable conv, fp64 math, accumulate 0.2x into out --------
__global__ __launch_bounds__(256) void deform_kd(
    const float* __restrict__ xin, const float* __restrict__ off,
    const float* __restrict__ dcw, float* out, int dil)
{
    __shared__ float Wsm[17*153];
    const int t = threadIdx.x;
    for (int e=t;e<17*153;e+=256) Wsm[e] = dcw[e];
    __syncthreads();
    const int p = blockIdx.x*256 + t;
    const int b = p / NPX, pi = p - b*NPX;
    const int yq = pi/72;
    const int yy = yq, xx = pi - yq*72;
    const float* img = xin + (size_t)b*17*NPX;
    const float* ob  = off + (size_t)b*306*NPX + pi;
    double acc[17];
    #pragma unroll
    for (int o=0;o<17;o++) acc[o]=0.0;
    for (int c=0;c<17;c++){
        const float* im = img + c*NPX;
        for (int k=0;k<9;k++){
            const double dy = (double)ob[((c*9+k)*2+0)*NPX];
            const double dx = (double)ob[((c*9+k)*2+1)*NPX];
            const double py  = (double)yy + dy + (double)((k/3-1)*dil);
            const double pxd = (double)xx + dx + (double)((k%3-1)*dil);
            const double y0f = floor(py), x0f = floor(pxd);
            const double wy = py - y0f, wx = pxd - x0f;
            const int y0 = (int)fmax(fmin(y0f, 97.0), -2.0);
            const int x0 = (int)fmax(fmin(x0f, 73.0), -2.0);
            const bool yv0 = (y0   >= 0) && (y0   < 96);
            const bool yv1 = (y0+1 >= 0) && (y0+1 < 96);
            const bool xv0 = (x0   >= 0) && (x0   < 72);
            const bool xv1 = (x0+1 >= 0) && (x0+1 < 72);
            const int yc0 = min(max(y0  ,0),95), yc1 = min(max(y0+1,0),95);
            const int xc0 = min(max(x0  ,0),71), xc1 = min(max(x0+1,0),71);
            const double v00 = (yv0&&xv0) ? (double)im[yc0*72+xc0] : 0.0;
            const double v01 = (yv0&&xv1) ? (double)im[yc0*72+xc1] : 0.0;
            const double v10 = (yv1&&xv0) ? (double)im[yc1*72+xc0] : 0.0;
            const double v11 = (yv1&&xv1) ? (double)im[yc1*72+xc1] : 0.0;
            const double s = v00*(1.0-wy)*(1.0-wx) + v01*(1.0-wy)*wx
                           + v10*wy*(1.0-wx)       + v11*wy*wx;
            const int ck = c*9+k;
            #pragma unroll
            for (int o=0;o<17;o++)
                acc[o] = fma((double)Wsm[o*153+ck], s, acc[o]);
        }
    }
    #pragma unroll
    for (int o=0;o<17;o++)
        atomicAdd(out + ((size_t)b*17+o)*NPX + pi, (float)(0.2*acc[o]));
}

extern "C" void kernel_launch(void* const* d_in, const int* in_sizes, int n_in,
                              void* d_out, int out_size, void* d_ws, size_t ws_size,
                              hipStream_t stream)
{
    const float* x    = (const float*)d_in[0];
    const float* y    = (const float*)d_in[1];
    const float* b0w1 = (const float*)d_in[2];
    const float* b0s1 = (const float*)d_in[3];
    const float* b0b1 = (const float*)d_in[4];
    const float* b0w2 = (const float*)d_in[5];
    const float* b0s2 = (const float*)d_in[6];
    const float* b0b2 = (const float*)d_in[7];
    const float* b0wd = (const float*)d_in[8];
    const float* b0sd = (const float*)d_in[9];
    const float* b0bd = (const float*)d_in[10];
    const float* bw1  = (const float*)d_in[11];
    const float* bs1  = (const float*)d_in[12];
    const float* bb1  = (const float*)d_in[13];
    const float* bw2  = (const float*)d_in[14];
    const float* bs2  = (const float*)d_in[15];
    const float* bb2  = (const float*)d_in[16];
    const float* offw = (const float*)d_in[17];
    const float* dcw  = (const float*)d_in[18];
    float* out = (float*)d_out;

    // ---- workspace layout (~85 MB) ----
    char* P = (char*)d_ws;
    auto nxt = [&](size_t bytes){ char* r = P; P += (bytes + 255) & ~(size_t)255; return r; };
    const size_t actLB = 4ull*2*7448*128*2;          // 15,253,504
    __hip_bfloat16* actL = (__hip_bfloat16*)nxt(actLB);
    double* hbuf = (double*)nxt(14155776);
    char*   R2   = nxt(35389440);                    // o | diff | res0, later bigL
    double* obuf  = (double*)R2;
    double* diffd = (double*)(R2 + 14155776);
    double* res0  = (double*)(R2 + 14155776 + 1880064);
    __hip_bfloat16* bigL = (__hip_bfloat16*)R2;
    const size_t bigLB = 4ull*2*17280*128*2;         // 35,389,440
    __hip_bfloat16* Bpk = (__hip_bfloat16*)nxt(2949120);
    int*  EbB  = (int*)nxt(1280);
    float* offb = (float*)nxt(16920576);
    u64*  maxbuf = (u64*)nxt(512);

    dim3 blk(256);
    hipMemsetAsync(actL, 0, actLB, stream);
    hipMemsetAsync(maxbuf, 0, 512, stream);
    hipMemsetAsync(d_out, 0, (size_t)out_size*sizeof(float), stream);

    hipLaunchKernelGGL(diff_kd, dim3(918), blk, 0, stream, x, y, diffd, 235008);
    hipLaunchKernelGGL(conv1x1_d, dim3(432), blk, 0, stream, diffd, b0wd, b0sd, b0bd, res0);
    hipLaunchKernelGGL((conv3x3d<double>), dim3(216,1), blk, 0, stream,
                       diffd, b0w1, b0s1, b0b1, (const double*)nullptr, obuf, 17, 128, 1, 1);
    hipLaunchKernelGGL(maxk, dim3(256), blk, 0, stream, obuf, 1769472, maxbuf, 0);
    hipLaunchKernelGGL(adecomp_k, dim3(216), blk, 0, stream, obuf, actL, maxbuf, 0, 7448, 76, 1);
    // blk0 conv2 (limb): feat0 = relu(bn(conv(o0)) + res0)
    hipLaunchKernelGGL(wprep_k, dim3(128), dim3(64), 0, stream, b0w2, Bpk, EbB, 128, 128);
    hipLaunchKernelGGL((convL<1>), dim3(216,2), blk, 0, stream,
                       actL, 7448, 76, 1, 1, Bpk, EbB, 128, 128, maxbuf, 0,
                       b0s2, b0b2, (const double*)res0, (void*)hbuf, maxbuf, 1);
    hipLaunchKernelGGL(adecomp_k, dim3(216), blk, 0, stream, hbuf, actL, maxbuf, 1, 7448, 76, 1);

    for (int i = 0; i < 19; i++){
        const int sIn1 = 2*i + 1, sO = 2*i + 2, sH = 2*i + 3;
        hipLaunchKernelGGL(wprep_k, dim3(128), dim3(64), 0, stream,
                           bw1 + (size_t)i*147456, Bpk, EbB, 128, 128);
        hipLaunchKernelGGL((convL<0>), dim3(216,2), blk, 0, stream,
                           actL, 7448, 76, 1, 1, Bpk, EbB, 128, 128, maxbuf, sIn1,
                           bs1 + i*128, bb1 + i*128, (const double*)nullptr,
                           (void*)obuf, maxbuf, sO);
        hipLaunchKernelGGL(adecomp_k, dim3(216), blk, 0, stream, obuf, actL, maxbuf, sO, 7448, 76, 1);
        hipLaunchKernelGGL(wprep_k, dim3(128), dim3(64), 0, stream,
                           bw2 + (size_t)i*147456, Bpk, EbB, 128, 128);
        hipLaunchKernelGGL((convL<1>), dim3(216,2), blk, 0, stream,
                           actL, 7448, 76, 1, 1, Bpk, EbB, 128, 128, maxbuf, sO,
                           bs2 + i*128, bb2 + i*128, (const double*)hbuf,
                           (void*)hbuf, maxbuf, sH);
        if (i < 18)
            hipLaunchKernelGGL(adecomp_k, dim3(216), blk, 0, stream, hbuf, actL, maxbuf, sH, 7448, 76, 1);
    }

    // offsets + deform (feat slot = 39)
    hipMemsetAsync(bigL, 0, bigLB, stream);
    hipLaunchKernelGGL(adecomp_k, dim3(216), blk, 0, stream, hbuf, bigL, maxbuf, 39, 17280, 120, 24);
    const int dils[5] = {3,6,12,18,24};
    for (int d = 0; d < 5; d++){
        hipLaunchKernelGGL(wprep_k, dim3(320), dim3(64), 0, stream,
                           offw + (size_t)d*352512, Bpk, EbB, 306, 320);
        hipLaunchKernelGGL((convL<2>), dim3(216,5), blk, 0, stream,
                           bigL, 17280, 120, 24, dils[d], Bpk, EbB, 320, 306, maxbuf, 39,
                           (const float*)nullptr, (const float*)nullptr,
                           (const double*)nullptr, (void*)offb, (u64*)nullptr, -1);
        hipLaunchKernelGGL(deform_kd, dim3(54), blk, 0, stream,
                           x, offb, dcw + (size_t)d*2601, out, dils[d]);
    }
}

// Round 5
// 7484.366 us; speedup vs baseline: 1.7620x; 1.7620x over previous
//
#include <hip/hip_runtime.h>
#include <hip/hip_bf16.h>

#define NPX 6912   // 96*72
typedef unsigned long long u64;
typedef short bf16x8 __attribute__((ext_vector_type(8)));
typedef float f32x4 __attribute__((ext_vector_type(4)));

__device__ __forceinline__ int ea_from_bits(u64 bits){
    double m = __longlong_as_double((long long)bits);
    if (!(m > 0.0)) return 0;
    return ilogb(m) + 1;
}
// balanced radix-256 digits of round(a*2^sh), |d|<=128, a exact in 4 digits
__device__ __forceinline__ void digits4(double a, int sh, int& d0, int& d1, int& d2, int& d3){
    long long q = __double2ll_rn(ldexp(a, sh));
    d3 = (int)(((q + 128) & 255) - 128); q = (q - d3) >> 8;
    d2 = (int)(((q + 128) & 255) - 128); q = (q - d2) >> 8;
    d1 = (int)(((q + 128) & 255) - 128);
    d0 = (int)((q - d1) >> 8);
}

// ---------------- diff = y - x (f64) + absmax -> maxbuf[slot] ----------------
__global__ __launch_bounds__(256) void diff_kd(const float* __restrict__ x,
    const float* __restrict__ y, double* __restrict__ d, int n,
    u64* maxbuf, int slot){
    int i = blockIdx.x*256 + threadIdx.x;
    double m = 0.0;
    if (i < n){ double v = (double)y[i] - (double)x[i]; d[i] = v; m = fabs(v); }
    #pragma unroll
    for (int o=32;o;o>>=1) m = fmax(m, __shfl_down(m,o));
    __shared__ double W[4];
    if ((threadIdx.x&63)==0) W[threadIdx.x>>6]=m;
    __syncthreads();
    if (threadIdx.x==0){
        m = fmax(fmax(W[0],W[1]),fmax(W[2],W[3]));
        atomicMax(maxbuf+slot,(u64)__double_as_longlong(m));
    }
}

// ---------------- 1x1 conv 17->128 + bn, fp64 ----------------
__global__ __launch_bounds__(256) void conv1x1_d(const double* __restrict__ in,
    const float* __restrict__ wgt, const float* __restrict__ scale,
    const float* __restrict__ shift, double* __restrict__ out){
    __shared__ float Ws[17*128];
    const int t = threadIdx.x;
    for (int e=t; e<17*128; e+=256){
        int ic = e >> 7, oc = e & 127;
        Ws[e] = wgt[oc*17 + ic];
    }
    __syncthreads();
    const int pxl = t & 31, ocg = t >> 5;
    const int p = blockIdx.x*32 + pxl;
    const int b = p / NPX, pi = p - b*NPX;
    double acc[16];
    #pragma unroll
    for (int j=0;j<16;j++) acc[j]=0.0;
    const double* inb = in + (size_t)b*17*NPX + pi;
    #pragma unroll
    for (int ic=0;ic<17;ic++){
        const double a = inb[(size_t)ic*NPX];
        #pragma unroll
        for (int j=0;j<16;j++) acc[j] = fma(a, (double)Ws[(ic<<7)+(ocg<<4)+j], acc[j]);
    }
    #pragma unroll
    for (int j=0;j<16;j++){
        const int oc = (ocg<<4)+j;
        out[((size_t)b*128+oc)*NPX + pi] = fma(acc[j], (double)scale[oc], (double)shift[oc]);
    }
}

// ---------------- activation decompose: f64 [2][128][NPX] -> bf16 [4][2][PS][128] ----
// grid 864 (2b x 432 sixteen-px groups), 256 thr
__global__ __launch_bounds__(256) void adecomp_k(const double* __restrict__ src,
    __hip_bfloat16* __restrict__ dst, const u64* __restrict__ maxbuf, int slot,
    int PS, int PW, int PB)
{
    __shared__ __hip_bfloat16 L[4][16][128];
    const int t = threadIdx.x;
    const int b = blockIdx.x / 432, px0 = (blockIdx.x % 432) * 16;
    const int sh = 30 - ea_from_bits(maxbuf[slot]);
    const int tp = t & 15, tc = t >> 4;
    #pragma unroll
    for (int i=0;i<8;i++){
        const int c = tc + i*16;
        double a = src[((size_t)b*128 + c)*NPX + px0 + tp];
        int d0,d1,d2,d3; digits4(a, sh, d0,d1,d2,d3);
        L[0][tp][c] = __float2bfloat16((float)d0);
        L[1][tp][c] = __float2bfloat16((float)d1);
        L[2][tp][c] = __float2bfloat16((float)d2);
        L[3][tp][c] = __float2bfloat16((float)d3);
    }
    __syncthreads();
    const int wic = t & 15, wpx = t >> 4;
    const int px = px0 + wpx, yy = px/72, xx = px - yy*72;
    const size_t pbase = ((size_t)(yy+PB)*PW + (xx+PB))*128 + wic*8;
    #pragma unroll
    for (int l=0;l<4;l++){
        const size_t po = ((size_t)(l*2+b)*PS)*128 + pbase;
        *(uint4*)(dst+po) = *(const uint4*)(&L[l][wpx][wic*8]);
    }
}

// ---------------- diff decompose: f64 [2][17][NPX] -> bf16 [4][2][7448][32] ----
__global__ __launch_bounds__(256) void adecomp17_k(const double* __restrict__ src,
    __hip_bfloat16* __restrict__ dst, const u64* __restrict__ maxbuf, int slot)
{
    __shared__ __hip_bfloat16 L[4][16][32];
    const int t = threadIdx.x;
    const int b = blockIdx.x / 432, px0 = (blockIdx.x % 432) * 16;
    const int sh = 30 - ea_from_bits(maxbuf[slot]);
    uint4 z = {0,0,0,0};
    *(uint4*)(((short*)L) + t*8) = z;   // zero all 2048 halfs
    __syncthreads();
    const int tp = t & 15, tc = t >> 4;
    #pragma unroll
    for (int i=0;i<2;i++){
        const int c = tc + i*16;
        if (c < 17){
            double a = src[((size_t)b*17 + c)*NPX + px0 + tp];
            int d0,d1,d2,d3; digits4(a, sh, d0,d1,d2,d3);
            L[0][tp][c] = __float2bfloat16((float)d0);
            L[1][tp][c] = __float2bfloat16((float)d1);
            L[2][tp][c] = __float2bfloat16((float)d2);
            L[3][tp][c] = __float2bfloat16((float)d3);
        }
    }
    __syncthreads();
    const int l = t >> 6, wpx = (t >> 2) & 15, chunk = t & 3;
    const int px = px0 + wpx, yy = px/72, xx = px - yy*72;
    const size_t po = ((size_t)(l*2+b)*7448 + (size_t)(yy+1)*76 + (xx+1))*32 + chunk*8;
    *(uint4*)(dst+po) = *(const uint4*)(&L[l][wpx][chunk*8]);
}

// ---------------- weight limb prepack: fp32 [ocw][ICw][9] -> bf16 [4][9][OCpad][ICpad] + Eb ----
__global__ __launch_bounds__(64) void wprep_k(const float* __restrict__ wgt,
    __hip_bfloat16* __restrict__ Bpk, int* __restrict__ Eb,
    int ocw, int ICw, int ICpad, int OCpad)
{
    const int oc = blockIdx.x, t = threadIdx.x;
    const int NW = ICw*9;
    float m = 0.f;
    if (oc < ocw)
        for (int e=t;e<NW;e+=64) m = fmaxf(m, fabsf(wgt[(size_t)oc*NW+e]));
    #pragma unroll
    for (int o=32;o;o>>=1) m = fmaxf(m, __shfl_down(m,o));
    m = __shfl(m, 0);
    const int Ebv = (m>0.f)?(ilogbf(m)+1):0;
    if (t==0) Eb[oc]=Ebv;
    const int sh = 30 - Ebv;
    const size_t bLimb = (size_t)9*OCpad*ICpad;
    const int nchunks = (ICpad>>3)*9;
    for (int mci=t; mci<nchunks; mci+=64){
        const int ic8 = mci % (ICpad>>3), tap = mci / (ICpad>>3);
        __align__(16) __hip_bfloat16 dig[4][8];
        #pragma unroll
        for (int j=0;j<8;j++){
            const int ic = ic8*8+j;
            float w = (oc<ocw && ic<ICw) ? wgt[((size_t)oc*ICw+ic)*9+tap] : 0.f;
            int d0,d1,d2,d3; digits4((double)w, sh, d0,d1,d2,d3);
            dig[0][j]=__float2bfloat16((float)d0);
            dig[1][j]=__float2bfloat16((float)d1);
            dig[2][j]=__float2bfloat16((float)d2);
            dig[3][j]=__float2bfloat16((float)d3);
        }
        const size_t base = ((size_t)tap*OCpad+oc)*ICpad + ic8*8;
        #pragma unroll
        for (int l=0;l<4;l++)
            *(uint4*)(Bpk + l*bLimb + base) = *(const uint4*)(&dig[l][0]);
    }
}

// ---------------- exact limb-MFMA 3x3 dilated conv, direct fragment loads ----------------
// 1 wave/block (64 thr), tile 32px x 32oc. grid (432 = 2b*216, OCpad/32).
// MODE 0: relu(bn(conv)) -> f64 + max ; 1: relu(bn(conv)+res) -> f64 + max ; 2: raw -> f32
#define MF(A,B,C) __builtin_amdgcn_mfma_f32_16x16x32_bf16(A,B,C,0,0,0)
#define DRAIN(CS, WT) do { \
  _Pragma("unroll") for (int mt_=0; mt_<2; mt_++){ \
  _Pragma("unroll") for (int nt_=0; nt_<2; nt_++){ \
  _Pragma("unroll") for (int v_=0; v_<4; v_++){ \
    cr[mt_][nt_][v_] += (double)CS[mt_][nt_][v_]*(WT); CS[mt_][nt_][v_] = 0.f; } } } } while(0)

template<int MODE, int ICC>
__global__ __launch_bounds__(64, 2) void convL(
    const __hip_bfloat16* __restrict__ inL, int PS, int PW, int PB, int dil,
    const __hip_bfloat16* __restrict__ Bpk, const int* __restrict__ Eb,
    int OCpad, int OCw,
    const u64* __restrict__ maxbuf, int easlot,
    const float* __restrict__ scale, const float* __restrict__ shift,
    const double* res, void* outp, u64* maxout, int moslot)
{
    constexpr int CC = ICC*32;
    const int lane = threadIdx.x;
    const int ocl = lane & 15, rq = lane >> 4;
    const int b = blockIdx.x / 216, px0 = (blockIdx.x % 216) * 32;
    const int oc0 = blockIdx.y * 32;

    long long aBase[2];
    #pragma unroll
    for (int mt=0; mt<2; mt++){
        const int px = px0 + mt*16 + ocl;
        const int sy = px/72, sx = px - sy*72;
        aBase[mt] = ((long long)b*PS + (long long)(sy+PB)*PW + (sx+PB))*CC + rq*8;
    }
    const long long pStr = (long long)2*PS*CC;
    const size_t bLimb = (size_t)9*OCpad*CC;
    size_t bBase[2];
    #pragma unroll
    for (int nt=0; nt<2; nt++)
        bBase[nt] = ((size_t)(oc0 + nt*16 + ocl))*CC + rq*8;

    f32x4 c0[2][2], c1[2][2], c2[2][2], c3[2][2];
    double cr[2][2][4];
    #pragma unroll
    for (int i=0;i<2;i++)
      #pragma unroll
      for (int j=0;j<2;j++){
        c0[i][j]=(f32x4)(0.f); c1[i][j]=(f32x4)(0.f);
        c2[i][j]=(f32x4)(0.f); c3[i][j]=(f32x4)(0.f);
        #pragma unroll
        for (int v=0;v<4;v++) cr[i][j][v]=0.0;
      }

    const int Ea = ea_from_bits(maxbuf[easlot]);

    for (int tap=0; tap<9; tap++){
        const int ty = tap/3, tx = tap - ty*3;
        const long long dofs = ((long long)(ty-1)*PW + (tx-1)) * dil * CC;
        const size_t bTap = (size_t)tap*OCpad*CC;
        #pragma unroll
        for (int icc=0; icc<ICC; icc++){
            bf16x8 af[2][4], bfr[2][4];
            #pragma unroll
            for (int l=0;l<4;l++){
                #pragma unroll
                for (int mt=0;mt<2;mt++)
                    af[mt][l] = *(const bf16x8*)(inL + (aBase[mt] + dofs + icc*32 + l*pStr));
                #pragma unroll
                for (int nt=0;nt<2;nt++)
                    bfr[nt][l] = *(const bf16x8*)(Bpk + ((size_t)l*bLimb + bTap + bBase[nt] + icc*32));
            }
            __builtin_amdgcn_s_setprio(1);
            #pragma unroll
            for (int nt=0;nt<2;nt++)
              #pragma unroll
              for (int mt=0;mt<2;mt++){
                c0[mt][nt] = MF(af[mt][0], bfr[nt][0], c0[mt][nt]);
                c1[mt][nt] = MF(af[mt][0], bfr[nt][1], c1[mt][nt]);
                c1[mt][nt] = MF(af[mt][1], bfr[nt][0], c1[mt][nt]);
                c2[mt][nt] = MF(af[mt][0], bfr[nt][2], c2[mt][nt]);
                c2[mt][nt] = MF(af[mt][1], bfr[nt][1], c2[mt][nt]);
                c2[mt][nt] = MF(af[mt][2], bfr[nt][0], c2[mt][nt]);
                c3[mt][nt] = MF(af[mt][0], bfr[nt][3], c3[mt][nt]);
                c3[mt][nt] = MF(af[mt][1], bfr[nt][2], c3[mt][nt]);
                c3[mt][nt] = MF(af[mt][2], bfr[nt][1], c3[mt][nt]);
                c3[mt][nt] = MF(af[mt][3], bfr[nt][0], c3[mt][nt]);
              }
            __builtin_amdgcn_s_setprio(0);
            // provably-exact drain schedule (worst-case |partial| < 2^24)
            if (ICC==4){
                if (icc==3){
                    DRAIN(c3, 0x1p-24);
                    if (tap&1){ DRAIN(c2, 0x1p-16); DRAIN(c1, 0x1p-8); }
                    if (tap==3){ DRAIN(c0, 1.0); }
                }
            } else {
                if (tap&1) DRAIN(c3, 0x1p-24);
                if ((tap&3)==3){ DRAIN(c2, 0x1p-16); DRAIN(c1, 0x1p-8); }
            }
        }
    }
    DRAIN(c0, 1.0); DRAIN(c1, 0x1p-8); DRAIN(c2, 0x1p-16); DRAIN(c3, 0x1p-24);

    if (MODE != 2){
        double mx = 0.0;
        #pragma unroll
        for (int nt=0;nt<2;nt++){
            const int oc = oc0 + nt*16 + ocl;
            const int ex = Ea + Eb[oc] - 12;
            const double sc = (double)scale[oc], sf = (double)shift[oc];
            #pragma unroll
            for (int mt=0;mt<2;mt++){
                const size_t ob = ((size_t)(b*128+oc))*NPX + px0 + mt*16 + rq*4;
                double4 rv;
                if (MODE==1) rv = *(const double4*)(res+ob);
                double vv[4];
                #pragma unroll
                for (int v=0;v<4;v++){
                    double dv = fma(ldexp(cr[mt][nt][v], ex), sc, sf);
                    if (MODE==1) dv += (&rv.x)[v];
                    dv = dv>0.0 ? dv : 0.0;
                    vv[v]=dv; mx = fmax(mx,dv);
                }
                double4 st = {vv[0],vv[1],vv[2],vv[3]};
                *(double4*)((double*)outp+ob) = st;
            }
        }
        #pragma unroll
        for (int o=32;o;o>>=1) mx = fmax(mx,__shfl_down(mx,o));
        if (lane==0) atomicMax(maxout+moslot,(u64)__double_as_longlong(mx));
    } else {
        #pragma unroll
        for (int nt=0;nt<2;nt++){
            const int oc = oc0 + nt*16 + ocl;
            if (oc < OCw){
                const int ex = Ea + Eb[oc] - 12;
                #pragma unroll
                for (int mt=0;mt<2;mt++){
                    const size_t ob = ((size_t)b*OCw+oc)*NPX + px0 + mt*16 + rq*4;
                    float4 st;
                    #pragma unroll
                    for (int v=0;v<4;v++)
                        (&st.x)[v] = (float)ldexp(cr[mt][nt][v], ex);
                    *(float4*)((float*)outp+ob) = st;
                }
            }
        }
    }
}

// ---------------- deformable conv, fp64 math, c-split x4, accumulate 0.2x into out ----
__global__ __launch_bounds__(256) void deform_kd(
    const float* __restrict__ xin, const float* __restrict__ off,
    const float* __restrict__ dcw, float* out, int dil)
{
    __shared__ float Wsm[17*153];
    const int t = threadIdx.x;
    for (int e=t;e<17*153;e+=256) Wsm[e] = dcw[e];
    __syncthreads();
    const int spx = t & 63, cg = t >> 6;
    const int p = blockIdx.x*64 + spx;      // 216*64 = 13824
    const int b = p / NPX, pi = p - b*NPX;
    const int yy = pi/72, xx = pi - yy*72;
    const float* img = xin + (size_t)b*17*NPX;
    const float* ob  = off + (size_t)b*306*NPX + pi;
    const int cbeg = cg ? (4*cg+1) : 0;
    const int cend = cbeg + (cg ? 4 : 5);
    double acc[17];
    #pragma unroll
    for (int o=0;o<17;o++) acc[o]=0.0;
    for (int c=cbeg;c<cend;c++){
        const float* im = img + c*NPX;
        #pragma unroll
        for (int k=0;k<9;k++){
            const double dy = (double)ob[((c*9+k)*2+0)*NPX];
            const double dx = (double)ob[((c*9+k)*2+1)*NPX];
            const double py  = (double)yy + dy + (double)((k/3-1)*dil);
            const double pxd = (double)xx + dx + (double)((k%3-1)*dil);
            const double y0f = floor(py), x0f = floor(pxd);
            const double wy = py - y0f, wx = pxd - x0f;
            const int y0 = (int)fmax(fmin(y0f, 97.0), -2.0);
            const int x0 = (int)fmax(fmin(x0f, 73.0), -2.0);
            const bool yv0 = (y0   >= 0) && (y0   < 96);
            const bool yv1 = (y0+1 >= 0) && (y0+1 < 96);
            const bool xv0 = (x0   >= 0) && (x0   < 72);
            const bool xv1 = (x0+1 >= 0) && (x0+1 < 72);
            const int yc0 = min(max(y0  ,0),95), yc1 = min(max(y0+1,0),95);
            const int xc0 = min(max(x0  ,0),71), xc1 = min(max(x0+1,0),71);
            const double v00 = (yv0&&xv0) ? (double)im[yc0*72+xc0] : 0.0;
            const double v01 = (yv0&&xv1) ? (double)im[yc0*72+xc1] : 0.0;
            const double v10 = (yv1&&xv0) ? (double)im[yc1*72+xc0] : 0.0;
            const double v11 = (yv1&&xv1) ? (double)im[yc1*72+xc1] : 0.0;
            const double s = v00*(1.0-wy)*(1.0-wx) + v01*(1.0-wy)*wx
                           + v10*wy*(1.0-wx)       + v11*wy*wx;
            const int ck = c*9+k;
            #pragma unroll
            for (int o=0;o<17;o++)
                acc[o] = fma((double)Wsm[o*153+ck], s, acc[o]);
        }
    }
    #pragma unroll
    for (int o=0;o<17;o++)
        atomicAdd(out + ((size_t)b*17+o)*NPX + pi, (float)(0.2*acc[o]));
}

extern "C" void kernel_launch(void* const* d_in, const int* in_sizes, int n_in,
                              void* d_out, int out_size, void* d_ws, size_t ws_size,
                              hipStream_t stream)
{
    const float* x    = (const float*)d_in[0];
    const float* y    = (const float*)d_in[1];
    const float* b0w1 = (const float*)d_in[2];
    const float* b0s1 = (const float*)d_in[3];
    const float* b0b1 = (const float*)d_in[4];
    const float* b0w2 = (const float*)d_in[5];
    const float* b0s2 = (const float*)d_in[6];
    const float* b0b2 = (const float*)d_in[7];
    const float* b0wd = (const float*)d_in[8];
    const float* b0sd = (const float*)d_in[9];
    const float* b0bd = (const float*)d_in[10];
    const float* bw1  = (const float*)d_in[11];
    const float* bs1  = (const float*)d_in[12];
    const float* bb1  = (const float*)d_in[13];
    const float* bw2  = (const float*)d_in[14];
    const float* bs2  = (const float*)d_in[15];
    const float* bb2  = (const float*)d_in[16];
    const float* offw = (const float*)d_in[17];
    const float* dcw  = (const float*)d_in[18];
    float* out = (float*)d_out;

    // ---- workspace (~70 MB) ----
    char* P = (char*)d_ws;
    auto nxt = [&](size_t bytes){ char* r = P; P += (bytes + 255) & ~(size_t)255; return r; };
    double* hbuf = (double*)nxt(14155776);            // h_i f64, persistent
    __hip_bfloat16* Bpk = (__hip_bfloat16*)nxt(2949120);
    int*  EbB  = (int*)nxt(1280);
    u64*  maxbuf = (u64*)nxt(512);
    char* R0 = nxt(52310016);                         // overlapped region
    // trunk phase:
    __hip_bfloat16* actL  = (__hip_bfloat16*)R0;                    // 15,253,504
    __hip_bfloat16* diffL = (__hip_bfloat16*)(R0 + 15253504);       //  3,813,376
    double* diffd = (double*)(R0 + 15253504 + 3813376);             //  1,880,064
    double* res0  = (double*)(R0 + 15253504 + 3813376 + 1880064);   // 14,155,776
    double* obuf  = (double*)(R0 + 15253504 + 3813376 + 1880064 + 14155776); // 14,155,776
    // offsets phase (reuses R0; trunk buffers except hbuf are dead by then):
    __hip_bfloat16* bigL = (__hip_bfloat16*)R0;                     // 35,389,440
    float* offb = (float*)(R0 + 35389440);                          // 16,920,576
    const size_t actLB = 15253504, diffLB = 3813376, bigLB = 35389440;

    dim3 b256(256);
    hipMemsetAsync(actL, 0, actLB, stream);
    hipMemsetAsync(diffL, 0, diffLB, stream);
    hipMemsetAsync(maxbuf, 0, 512, stream);
    hipMemsetAsync(d_out, 0, (size_t)out_size*sizeof(float), stream);

    // diff (+max slot 40), res0
    hipLaunchKernelGGL(diff_kd, dim3(918), b256, 0, stream, x, y, diffd, 235008, maxbuf, 40);
    hipLaunchKernelGGL(conv1x1_d, dim3(432), b256, 0, stream, diffd, b0wd, b0sd, b0bd, res0);
    // blk0 conv1 (limb, 17ch): o0 = relu(bn(conv(diff))) -> obuf, max slot 0
    hipLaunchKernelGGL(adecomp17_k, dim3(864), b256, 0, stream, diffd, diffL, maxbuf, 40);
    hipLaunchKernelGGL(wprep_k, dim3(128), dim3(64), 0, stream, b0w1, Bpk, EbB, 128, 17, 32, 128);
    hipLaunchKernelGGL((convL<0,1>), dim3(432,4), dim3(64), 0, stream,
                       diffL, 7448, 76, 1, 1, Bpk, EbB, 128, 128, maxbuf, 40,
                       b0s1, b0b1, (const double*)nullptr, (void*)obuf, maxbuf, 0);
    hipLaunchKernelGGL(adecomp_k, dim3(864), b256, 0, stream, obuf, actL, maxbuf, 0, 7448, 76, 1);
    // blk0 conv2: h0 = relu(bn(conv(o0)) + res0) -> hbuf, max slot 1
    hipLaunchKernelGGL(wprep_k, dim3(128), dim3(64), 0, stream, b0w2, Bpk, EbB, 128, 128, 128, 128);
    hipLaunchKernelGGL((convL<1,4>), dim3(432,4), dim3(64), 0, stream,
                       actL, 7448, 76, 1, 1, Bpk, EbB, 128, 128, maxbuf, 0,
                       b0s2, b0b2, (const double*)res0, (void*)hbuf, maxbuf, 1);
    hipLaunchKernelGGL(adecomp_k, dim3(864), b256, 0, stream, hbuf, actL, maxbuf, 1, 7448, 76, 1);

    for (int i = 0; i < 19; i++){
        const int sIn = 2*i + 1, sO = 2*i + 2, sH = 2*i + 3;
        hipLaunchKernelGGL(wprep_k, dim3(128), dim3(64), 0, stream,
                           bw1 + (size_t)i*147456, Bpk, EbB, 128, 128, 128, 128);
        hipLaunchKernelGGL((convL<0,4>), dim3(432,4), dim3(64), 0, stream,
                           actL, 7448, 76, 1, 1, Bpk, EbB, 128, 128, maxbuf, sIn,
                           bs1 + i*128, bb1 + i*128, (const double*)nullptr,
                           (void*)obuf, maxbuf, sO);
        hipLaunchKernelGGL(adecomp_k, dim3(864), b256, 0, stream, obuf, actL, maxbuf, sO, 7448, 76, 1);
        hipLaunchKernelGGL(wprep_k, dim3(128), dim3(64), 0, stream,
                           bw2 + (size_t)i*147456, Bpk, EbB, 128, 128, 128, 128);
        hipLaunchKernelGGL((convL<1,4>), dim3(432,4), dim3(64), 0, stream,
                           actL, 7448, 76, 1, 1, Bpk, EbB, 128, 128, maxbuf, sO,
                           bs2 + i*128, bb2 + i*128, (const double*)hbuf,
                           (void*)hbuf, maxbuf, sH);
        if (i < 18)
            hipLaunchKernelGGL(adecomp_k, dim3(864), b256, 0, stream, hbuf, actL, maxbuf, sH, 7448, 76, 1);
    }

    // offsets + deform (feat = hbuf, max slot 39)
    hipMemsetAsync(bigL, 0, bigLB, stream);
    hipLaunchKernelGGL(adecomp_k, dim3(864), b256, 0, stream, hbuf, bigL, maxbuf, 39, 17280, 120, 24);
    const int dils[5] = {3,6,12,18,24};
    for (int d = 0; d < 5; d++){
        hipLaunchKernelGGL(wprep_k, dim3(320), dim3(64), 0, stream,
                           offw + (size_t)d*352512, Bpk, EbB, 306, 128, 128, 320);
        hipLaunchKernelGGL((convL<2,4>), dim3(432,10), dim3(64), 0, stream,
                           bigL, 17280, 120, 24, dils[d], Bpk, EbB, 320, 306, maxbuf, 39,
                           (const float*)nullptr, (const float*)nullptr,
                           (const double*)nullptr, (void*)offb, (u64*)nullptr, 0);
        hipLaunchKernelGGL(deform_kd, dim3(216), b256, 0, stream,
                           x, offb, dcw + (size_t)d*2601, out, dils[d]);
    }
}